// Round 5
// baseline (302.356 us; speedup 1.0000x reference)
//
#include <hip/hip_runtime.h>

#define EPS 1e-10f
#define BLOCK 256
#define GRID1 1024    // R9: halve resident streams (was 2048)
#define BGROUPS 1024  // float4 groups per block per sweep (= 4 * BLOCK)

// R9. R8 post-mortem: both-streams-nt -> stage1 ~79us @ 4.16 TB/s pure HBM
// read (dropped out of rocprof top-5; wall 320->302). Mixed LLC/HBM lockstep
// (R7) was the limiter, not an inbound ceiling. Memset on same chip: 6.8 TB/s
// -> read headroom plausible. Last CU-independent lever: DRAM row locality.
// 2048 blocks x 2 arrays = 4096 concurrent 16KB streams ~ 16/channel ->
// row-buffer conflicts. R9 single change: GRID 2048->1024 (4 blocks/CU, still
// 16 waves/CU; 2048 streams). Null => 4.16 TB/s is the nt-read ceiling for
// this shape => ROOFLINE (remaining wall is harness memsets ~220us).

typedef float f32x4 __attribute__((ext_vector_type(4)));
typedef int   i32x4 __attribute__((ext_vector_type(4)));

__global__ __launch_bounds__(BLOCK) void sparse_loss_stage1(
    const float* __restrict__ pred,
    const int* __restrict__ y,
    const int* __restrict__ lamda_p,
    float* __restrict__ partials,   // [GRID1]
    long long nvec,                 // number of float4 groups
    long long total) {              // total element count
  const float lam = (float)(*lamda_p);
  float acc = 0.0f;  // accumulates +coef*log(arg); sign applied in stage 2

  const f32x4* __restrict__ pv = reinterpret_cast<const f32x4*>(pred);
  const i32x4* __restrict__ yv = reinterpret_cast<const i32x4*>(y);

  // Bijective XCD-chunked swizzle (1024 % 8 == 0): XCD k owns blocks
  // [k*128, (k+1)*128) of the swizzled id space -> contiguous address chunk.
  const int bid = (int)((blockIdx.x & 7) * (GRID1 / 8) + (blockIdx.x >> 3));

#define ELEM(P, Y)                                   \
  {                                                  \
    const bool z = ((Y) == 0);                       \
    const float a = EPS + (z ? (1.0f - (P)) : (P));  \
    const float c = z ? 1.0f : lam;                  \
    acc = fmaf(c, __logf(a), acc);                   \
  }
#define ELEM4(A, B) ELEM(A[0], B[0]) ELEM(A[1], B[1]) ELEM(A[2], B[2]) ELEM(A[3], B[3])

#define ELEMM(P, Y, M)                               \
  {                                                  \
    const bool z = ((Y) == 0);                       \
    const float a = EPS + (z ? (1.0f - (P)) : (P));  \
    const float c = (z ? 1.0f : lam) * (M);          \
    acc = fmaf(c, __logf(a), acc);                   \
  }
#define ELEM4M(A, B, M) \
  ELEMM(A[0], B[0], M) ELEMM(A[1], B[1], M) ELEMM(A[2], B[2], M) ELEMM(A[3], B[3], M)

  const long long SWEEP = (long long)GRID1 * BGROUPS;  // groups per full sweep
  const long long nfull = nvec / SWEEP;
  const long long j0 = (long long)bid * BGROUPS + threadIdx.x;

  // ---- full sweeps: 8 independent nt dwordx4 loads, compiler-scheduled ----
  for (long long s = 0; s < nfull; ++s) {
    const long long b = s * SWEEP + j0;
    const f32x4* pp = pv + b;
    const i32x4* yp = yv + b;
    f32x4 a0, a1, a2, a3;
    i32x4 q0, q1, q2, q3;
    a0 = __builtin_nontemporal_load(pp);
    a1 = __builtin_nontemporal_load(pp + 256);
    a2 = __builtin_nontemporal_load(pp + 512);
    a3 = __builtin_nontemporal_load(pp + 768);
    q0 = __builtin_nontemporal_load(yp);
    q1 = __builtin_nontemporal_load(yp + 256);
    q2 = __builtin_nontemporal_load(yp + 512);
    q3 = __builtin_nontemporal_load(yp + 768);
    ELEM4(a0, q0)
    ELEM4(a1, q1)
    ELEM4(a2, q2)
    ELEM4(a3, q3)
  }

  // ---- predicated remainder sweep (index-clamped, coef-masked) ----
  const long long rb = nfull * SWEEP;
  if (rb + (long long)bid * BGROUPS < nvec) {
    const long long b = rb + j0;
    const long long jA = b, jB = b + 256, jC = b + 512, jD = b + 768;
    const float mA = (jA < nvec) ? 1.0f : 0.0f;
    const float mB = (jB < nvec) ? 1.0f : 0.0f;
    const float mC = (jC < nvec) ? 1.0f : 0.0f;
    const float mD = (jD < nvec) ? 1.0f : 0.0f;
    const long long cA = (jA < nvec) ? jA : 0;
    const long long cB = (jB < nvec) ? jB : 0;
    const long long cC = (jC < nvec) ? jC : 0;
    const long long cD = (jD < nvec) ? jD : 0;
    f32x4 a0, a1, a2, a3;
    i32x4 q0, q1, q2, q3;
    a0 = __builtin_nontemporal_load(pv + cA);
    a1 = __builtin_nontemporal_load(pv + cB);
    a2 = __builtin_nontemporal_load(pv + cC);
    a3 = __builtin_nontemporal_load(pv + cD);
    q0 = __builtin_nontemporal_load(yv + cA);
    q1 = __builtin_nontemporal_load(yv + cB);
    q2 = __builtin_nontemporal_load(yv + cC);
    q3 = __builtin_nontemporal_load(yv + cD);
    ELEM4M(a0, q0, mA)
    ELEM4M(a1, q1, mB)
    ELEM4M(a2, q2, mC)
    ELEM4M(a3, q3, mD)
  }

  // ---- scalar tail (total % 4 != 0 -- not the case here, but cheap) ----
  const long long gtid = (long long)bid * BLOCK + threadIdx.x;
  const long long gstride = (long long)gridDim.x * BLOCK;
  for (long long j = nvec * 4 + gtid; j < total; j += gstride) {
    const float p = pred[j];
    ELEM(p, y[j])
  }
#undef ELEM
#undef ELEM4
#undef ELEMM
#undef ELEM4M

  // wave64 butterfly reduce
  for (int off = 32; off > 0; off >>= 1)
    acc += __shfl_down(acc, off, 64);

  __shared__ float ssum[4];
  const int lane = threadIdx.x & 63;
  const int wave = threadIdx.x >> 6;
  if (lane == 0) ssum[wave] = acc;
  __syncthreads();

  if (threadIdx.x == 0)
    partials[bid] = ssum[0] + ssum[1] + ssum[2] + ssum[3];
}

__global__ __launch_bounds__(BLOCK) void sparse_loss_stage2(
    const float* __restrict__ partials,  // [GRID1]
    float* __restrict__ out,
    float inv_total) {
  float acc = 0.0f;
  for (int i = threadIdx.x; i < GRID1; i += BLOCK)
    acc += partials[i];

  for (int off = 32; off > 0; off >>= 1)
    acc += __shfl_down(acc, off, 64);

  __shared__ float ssum[4];
  const int lane = threadIdx.x & 63;
  const int wave = threadIdx.x >> 6;
  if (lane == 0) ssum[wave] = acc;
  __syncthreads();

  if (threadIdx.x == 0)
    out[0] = -(ssum[0] + ssum[1] + ssum[2] + ssum[3]) * inv_total;
}

extern "C" void kernel_launch(void* const* d_in, const int* in_sizes, int n_in,
                              void* d_out, int out_size, void* d_ws, size_t ws_size,
                              hipStream_t stream) {
  const float* pred = (const float*)d_in[0];
  const int* y = (const int*)d_in[1];
  const int* lamda = (const int*)d_in[2];
  float* out = (float*)d_out;
  float* partials = (float*)d_ws;  // 1024 floats = 4 KB scratch

  const long long total = (long long)in_sizes[0];
  const long long nvec = total / 4;
  const float inv_total = 1.0f / (float)total;

  sparse_loss_stage1<<<GRID1, BLOCK, 0, stream>>>(pred, y, lamda, partials,
                                                  nvec, total);
  sparse_loss_stage2<<<1, BLOCK, 0, stream>>>(partials, out, inv_total);
}